// Round 5
// baseline (506.560 us; speedup 1.0000x reference)
//
#include <hip/hip_runtime.h>
#include <hip/hip_bf16.h>
#include <stdint.h>

#define HFR 128
#define HTO 128
#define RW  8     // rows per agg wave

typedef short short8 __attribute__((ext_vector_type(8)));   // 8 bf16 = 4 VGPRs
typedef float f32x4  __attribute__((ext_vector_type(4)));   // MFMA C/D
typedef unsigned long long u64;
typedef unsigned int uint;

static __device__ __forceinline__ unsigned short f2bf(float x) {
    __hip_bfloat16 h = __float2bfloat16(x);
    return *reinterpret_cast<unsigned short*>(&h);
}
static __device__ __forceinline__ float bflo(uint x) {
    return __uint_as_float(x << 16);           // low bf16 -> f32
}
static __device__ __forceinline__ float bfhi(uint x) {
    return __uint_as_float(x & 0xffff0000u);   // high bf16 -> f32
}

// record: val[63:32] | row15[31:17] | col[16:0]   (col < 2^17, row mod 2^15)
static __device__ __forceinline__ u64 make_rec(float v, int row, int col) {
    return ((u64)__float_as_uint(v) << 32) |
           ((u64)((uint)row & 0x7FFFu) << 17) | (u64)(uint)col;
}

// ---------------------------------------------------------------------------
// zero the (r,dst) histogram
// ---------------------------------------------------------------------------
__global__ __launch_bounds__(256) void zero_i32(int* __restrict__ p, int n) {
    int i = blockIdx.x * 256 + threadIdx.x;
    if (i < n) p[i] = 0;
}

// ---------------------------------------------------------------------------
// fused: {row histogram (x4 batched) | nodes fp32->bf16 | weights -> frags}
// block ranges: [0,EB) count, [EB,EB+CB) conv_nodes, [EB+CB, +WB) conv_weights
// ---------------------------------------------------------------------------
__global__ __launch_bounds__(256)
void prep2(const int* __restrict__ rows, int* __restrict__ cnt, int nnz,
           const float* __restrict__ nodes, unsigned short* __restrict__ ndbf, int N,
           const float* __restrict__ weights, short8* __restrict__ Wf,
           int EB, int CB) {
    int b = blockIdx.x;
    int t = threadIdx.x;
    if (b < EB) {                       // histogram over row id, 4 edges/thread
        int e0 = (b * 256 + t) * 4;
        if (e0 + 4 <= nnz) {
            int4 rw = *reinterpret_cast<const int4*>(rows + e0);
            atomicAdd(&cnt[rw.x], 1);
            atomicAdd(&cnt[rw.y], 1);
            atomicAdd(&cnt[rw.z], 1);
            atomicAdd(&cnt[rw.w], 1);
        } else {
            for (int e = e0; e < nnz; ++e) atomicAdd(&cnt[rows[e]], 1);
        }
        return;
    }
    b -= EB;
    if (b < CB) {                       // nodes fp32 -> bf16, row-major
        int id = b * 256 + t;           // id over N*16 (8 feats each)
        if (id < N * 16) {
            int n  = id >> 4;
            int k8 = id & 15;
            const float4* s = reinterpret_cast<const float4*>(nodes);
            float4 v0 = s[(size_t)n * 32 + k8 * 2];
            float4 v1 = s[(size_t)n * 32 + k8 * 2 + 1];
            short8 sv;
            sv[0] = f2bf(v0.x); sv[1] = f2bf(v0.y); sv[2] = f2bf(v0.z); sv[3] = f2bf(v0.w);
            sv[4] = f2bf(v1.x); sv[5] = f2bf(v1.y); sv[6] = f2bf(v1.z); sv[7] = f2bf(v1.w);
            *reinterpret_cast<short8*>(&ndbf[(size_t)n * HFR + k8 * 8]) = sv;
        }
        return;
    }
    b -= CB;                            // weights -> fragment layout (16384 ids)
    int id = b * 256 + t;
    int lane = id & 63;
    int kk   = (id >> 6) & 3;
    int j    = (id >> 8) & 7;
    int r    = id >> 11;
    int m = lane & 15, q = lane >> 4;
    const float* src = weights + (((size_t)r * HFR) + j * 16 + m) * HTO + kk * 32 + q * 8;
    short8 sv;
#pragma unroll
    for (int e = 0; e < 8; ++e) sv[e] = f2bf(src[e]);
    Wf[((r * 4 + kk) * 8 + j) * 64 + lane] = sv;
}

// ---------------------------------------------------------------------------
// hierarchical exclusive scan (3 levels for 800K bins)
// ---------------------------------------------------------------------------
__global__ __launch_bounds__(256)
void scan_reduce(const int* __restrict__ cnt, int* __restrict__ bsum, int N) {
    __shared__ int s[256];
    int t = threadIdx.x;
    int i = blockIdx.x * 256 + t;
    s[t] = (i < N) ? cnt[i] : 0;
    __syncthreads();
    for (int off = 128; off > 0; off >>= 1) {
        if (t < off) s[t] += s[t + off];
        __syncthreads();
    }
    if (t == 0) bsum[blockIdx.x] = s[0];
}

__global__ __launch_bounds__(1024)
void scan_block(int* __restrict__ bsum, int nb) {
    __shared__ int s[1024];
    int t = threadIdx.x;
    s[t] = (t < nb) ? bsum[t] : 0;
    __syncthreads();
    for (int off = 1; off < 1024; off <<= 1) {
        int o = (t >= off) ? s[t - off] : 0;
        __syncthreads();
        s[t] += o;
        __syncthreads();
    }
    if (t < nb) bsum[t] = (t == 0) ? 0 : s[t - 1];
}

__global__ __launch_bounds__(256)
void scan_final(int* __restrict__ cnt, const int* __restrict__ bsum, int N) {
    __shared__ int s[256];
    int t = threadIdx.x;
    int i = blockIdx.x * 256 + t;
    int v = (i < N) ? cnt[i] : 0;
    s[t] = v;
    __syncthreads();
    for (int off = 1; off < 256; off <<= 1) {
        int o = (t >= off) ? s[t - off] : 0;
        __syncthreads();
        s[t] += o;
        __syncthreads();
    }
    int ex = ((t == 0) ? 0 : s[t - 1]) + bsum[blockIdx.x];
    if (i < N) cnt[i] = ex;     // cnt becomes the segment-start cursor
}

// ---------------------------------------------------------------------------
// counting-sort placement, 4 edges/thread (int4/float4 loads -> 4 independent
// atomic+scatter chains in flight). sorted[] ordered by row id (r*N+dst).
// ---------------------------------------------------------------------------
__global__ __launch_bounds__(256)
void place_kernel(const int* __restrict__ rows, const int* __restrict__ cols,
                  const float* __restrict__ vals,
                  int* __restrict__ cursor, u64* __restrict__ sorted, int nnz) {
    int i4 = blockIdx.x * 256 + threadIdx.x;
    int e0 = i4 * 4;
    if (e0 >= nnz) return;
    if (e0 + 4 <= nnz) {
        int4   rw = *reinterpret_cast<const int4*>(rows + e0);
        int4   cl = *reinterpret_cast<const int4*>(cols + e0);
        float4 vl = *reinterpret_cast<const float4*>(vals + e0);
        int p0 = atomicAdd(&cursor[rw.x], 1);
        int p1 = atomicAdd(&cursor[rw.y], 1);
        int p2 = atomicAdd(&cursor[rw.z], 1);
        int p3 = atomicAdd(&cursor[rw.w], 1);
        sorted[p0] = make_rec(vl.x, rw.x, cl.x);
        sorted[p1] = make_rec(vl.y, rw.y, cl.y);
        sorted[p2] = make_rec(vl.z, rw.z, cl.z);
        sorted[p3] = make_rec(vl.w, rw.w, cl.w);
    } else {
        for (int e = e0; e < nnz; ++e) {
            int pos = atomicAdd(&cursor[rows[e]], 1);
            sorted[pos] = make_rec(vals[e], rows[e], cols[e]);
        }
    }
}

// ---------------------------------------------------------------------------
// AGG v2: wave owns RW=8 consecutive rows; streams its contiguous edge range
// in unguarded batches of 8 (8 record loads -> 8 independent gathers), with
// wave-uniform row-boundary flush driven by the row15 tag in each record.
// Only 2 cursor reads per wave. Zero LDS, zero barriers.
// ---------------------------------------------------------------------------
__global__ __launch_bounds__(256)
void agg_kernel(const unsigned short* __restrict__ ndbf,
                const u64* __restrict__ sorted,
                const int* __restrict__ cursor,
                uint* __restrict__ aggp, int NR) {
    int gw   = blockIdx.x * 4 + (threadIdx.x >> 6);
    int lane = threadIdx.x & 63;
    int v0   = gw * RW;
    if (v0 >= NR) return;
    int vend = min(v0 + RW, NR);
    int nrows = vend - v0;

    const uint* nd32 = reinterpret_cast<const uint*>(ndbf);

    int e    = (v0 == 0) ? 0 : cursor[v0 - 1];
    int eend = cursor[vend - 1];

    uint  vtag = (uint)v0 & 0x7FFFu;
    int   cur  = 0;
    float a0 = 0.f, a1 = 0.f;

#define GATH(q)  nd32[(size_t)((uint)(q) & 0x1FFFFu) * 64 + lane]
#define PROC(q, x) {                                                          \
        int rd = (int)((((uint)(q) >> 17) - vtag) & 0x7FFFu);                 \
        while (cur < rd) {                                                    \
            aggp[(size_t)(v0 + cur) * 64 + lane] =                            \
                ((uint)f2bf(a1) << 16) | (uint)f2bf(a0);                      \
            a0 = 0.f; a1 = 0.f; ++cur;                                        \
        }                                                                     \
        float v = __uint_as_float((uint)((q) >> 32));                         \
        a0 = fmaf(bflo(x), v, a0); a1 = fmaf(bfhi(x), v, a1);                 \
    }

    for (; e + 8 <= eend; e += 8) {
        const u64* p = sorted + __builtin_amdgcn_readfirstlane(e);
        u64 q0 = p[0], q1 = p[1], q2 = p[2], q3 = p[3];
        u64 q4 = p[4], q5 = p[5], q6 = p[6], q7 = p[7];
        uint x0 = GATH(q0);
        uint x1 = GATH(q1);
        uint x2 = GATH(q2);
        uint x3 = GATH(q3);
        uint x4 = GATH(q4);
        uint x5 = GATH(q5);
        uint x6 = GATH(q6);
        uint x7 = GATH(q7);
        PROC(q0, x0) PROC(q1, x1) PROC(q2, x2) PROC(q3, x3)
        PROC(q4, x4) PROC(q5, x5) PROC(q6, x6) PROC(q7, x7)
    }
    for (; e < eend; ++e) {
        u64 q0 = sorted[e];
        uint x0 = GATH(q0);
        PROC(q0, x0)
    }
    for (; cur < nrows; ++cur) {
        aggp[(size_t)(v0 + cur) * 64 + lane] =
            ((uint)f2bf(a1) << 16) | (uint)f2bf(a0);
        a0 = 0.f; a1 = 0.f;
    }
#undef PROC
#undef GATH
}

// ---------------------------------------------------------------------------
// GEMM: out[n] = relu( sum_r W_r * agg[r*N+n] ), registers across r.
// (unchanged from round 4 — numerically verified)
// ---------------------------------------------------------------------------
__global__ __launch_bounds__(256)
void gemm_kernel(const uint* __restrict__ aggp, const short8* __restrict__ Wf,
                 float* __restrict__ out, int N, int R) {
    const int t    = threadIdx.x;
    const int lane = t & 63;
    const int w    = t >> 6;
    const int m    = lane & 15;
    const int quad = lane >> 4;
    const int nb   = blockIdx.x * 128 + w * 32;   // wave's 32-node base

    f32x4 acc[2][8];
#pragma unroll
    for (int s = 0; s < 2; ++s)
#pragma unroll
        for (int j = 0; j < 8; ++j) acc[s][j] = (f32x4)(0.f);

    for (int r = 0; r < R; ++r) {
        short8 b[2][4];
#pragma unroll
        for (int s = 0; s < 2; ++s) {
            int n = nb + s * 16 + m;
            if (n < N) {
                const short8* rowp = reinterpret_cast<const short8*>(
                    aggp + ((size_t)r * N + n) * 64);
#pragma unroll
                for (int kk = 0; kk < 4; ++kk) b[s][kk] = rowp[kk * 4 + quad];
            } else {
#pragma unroll
                for (int kk = 0; kk < 4; ++kk) b[s][kk] = (short8)(short)0;
            }
        }
        const short8* wr = Wf + (size_t)r * 2048 + lane;
#pragma unroll
        for (int kk = 0; kk < 4; ++kk)
#pragma unroll
            for (int j = 0; j < 8; ++j) {
                short8 aw = wr[kk * 512 + j * 64];
                acc[0][j] = __builtin_amdgcn_mfma_f32_16x16x32_bf16(aw, b[0][kk], acc[0][j], 0, 0, 0);
                acc[1][j] = __builtin_amdgcn_mfma_f32_16x16x32_bf16(aw, b[1][kk], acc[1][j], 0, 0, 0);
            }
    }

#pragma unroll
    for (int s = 0; s < 2; ++s) {
        int n = nb + s * 16 + m;
        if (n < N) {
#pragma unroll
            for (int j = 0; j < 8; ++j) {
                float4 o;
                o.x = fmaxf(acc[s][j][0], 0.f);
                o.y = fmaxf(acc[s][j][1], 0.f);
                o.z = fmaxf(acc[s][j][2], 0.f);
                o.w = fmaxf(acc[s][j][3], 0.f);
                *reinterpret_cast<float4*>(out + (size_t)n * HTO + j * 16 + quad * 4) = o;
            }
        }
    }
}

// ---------------------------------------------------------------------------
extern "C" void kernel_launch(void* const* d_in, const int* in_sizes, int n_in,
                              void* d_out, int out_size, void* d_ws, size_t ws_size,
                              hipStream_t stream) {
    const float* nodes   = (const float*)d_in[0];   // [N, HFR] fp32
    const int*   indices = (const int*)d_in[1];     // [2, NNZ] int32
    const float* vals    = (const float*)d_in[2];   // [NNZ] fp32
    const float* weights = (const float*)d_in[3];   // [R, HFR, HTO] fp32

    const int N   = in_sizes[0] / HFR;
    const int nnz = in_sizes[1] / 2;
    const int R   = in_sizes[3] / (HFR * HTO);
    const int NR  = N * R;

    const int* rows = indices;
    const int* cols = indices + nnz;

    // ws (217.9 MB): aggp [NR,128] bf16 | sorted [nnz] u64 | Wf 256KB
    char* ws = (char*)d_ws;
    uint* aggp = (uint*)ws;                          // NR * 64 uints
    size_t off = (size_t)NR * 64 * sizeof(uint);
    u64* sorted = (u64*)(ws + off);
    off += (size_t)nnz * sizeof(u64);
    short8* Wf = (short8*)(ws + off);

    // d_out scratch (28.8 MB, all dead before gemm writes out):
    //   ndbf [N,HFR] bf16 | cnt [NR] int | b1 | b2
    char* ob = (char*)d_out;
    unsigned short* ndbf = (unsigned short*)ob;
    size_t ooff = (size_t)N * HFR * sizeof(unsigned short);
    int* cnt = (int*)(ob + ooff);
    ooff += (size_t)NR * sizeof(int);
    const int NB1 = (NR + 255) / 256;                // 3125
    int* b1 = (int*)(ob + ooff);
    ooff += (size_t)NB1 * sizeof(int);
    int* b2 = (int*)(ob + ooff);

    float* out = (float*)d_out;

    const int EB  = (nnz / 4 + 255) / 256;           // 1563 (x4-batched count)
    const int CB  = (N * 16 + 255) / 256;            // 6250
    const int WB  = (R * 4 * 8 * 64) / 256;          // 64
    const int NB2 = (NB1 + 255) / 256;               // 13
    const int PB  = (nnz / 4 + 255) / 256;           // 1563 place blocks
    const int AB  = ((NR + RW - 1) / RW + 3) / 4;    // 25000 agg blocks
    const int GB  = (N + 127) / 128;                 // 782 gemm blocks

    // 1) zero histogram
    zero_i32<<<NB1, 256, 0, stream>>>(cnt, NR);
    // 2) fused: row histogram | nodes->bf16 | weights->frags
    prep2<<<EB + CB + WB, 256, 0, stream>>>(rows, cnt, nnz, nodes, ndbf, N,
                                            weights, Wf, EB, CB);
    // 3) 3-level exclusive scan of 800K counters
    scan_reduce<<<NB1, 256, 0, stream>>>(cnt, b1, NR);
    scan_reduce<<<NB2, 256, 0, stream>>>(b1, b2, NB1);
    scan_block<<<1, 1024, 0, stream>>>(b2, NB2);
    scan_final<<<NB2, 256, 0, stream>>>(b1, b2, NB1);
    scan_final<<<NB1, 256, 0, stream>>>(cnt, b1, NR);
    // 4) counting-sort placement (x4-batched, sorted by row id)
    place_kernel<<<PB, 256, 0, stream>>>(rows, cols, vals, cnt, sorted, nnz);
    // 5) aggregate (edge-streaming, batched gathers)
    agg_kernel<<<AB, 256, 0, stream>>>(ndbf, sorted, cnt, aggp, NR);
    // 6) batched GEMM over relations + relu
    gemm_kernel<<<GB, 256, 0, stream>>>(aggp, Wf, out, N, R);
}

// Round 7
// 471.579 us; speedup vs baseline: 1.0742x; 1.0742x over previous
//
#include <hip/hip_runtime.h>
#include <hip/hip_bf16.h>
#include <stdint.h>

#define HFR 128
#define HTO 128
#define RW  8     // rows per agg wave

typedef short short8 __attribute__((ext_vector_type(8)));   // 8 bf16 = 4 VGPRs
typedef float f32x4  __attribute__((ext_vector_type(4)));   // MFMA C/D
typedef unsigned long long u64;
typedef unsigned int uint;

static __device__ __forceinline__ unsigned short f2bf(float x) {
    __hip_bfloat16 h = __float2bfloat16(x);
    return *reinterpret_cast<unsigned short*>(&h);
}
static __device__ __forceinline__ float bflo(uint x) {
    return __uint_as_float(x << 16);           // low bf16 -> f32
}
static __device__ __forceinline__ float bfhi(uint x) {
    return __uint_as_float(x & 0xffff0000u);   // high bf16 -> f32
}

// record: val[63:32] | row15[31:17] | col[16:0]   (col < 2^17, row mod 2^15)
static __device__ __forceinline__ u64 make_rec(float v, int row, int col) {
    return ((u64)__float_as_uint(v) << 32) |
           ((u64)((uint)row & 0x7FFFu) << 17) | (u64)(uint)col;
}

// ---------------------------------------------------------------------------
// zero the (r,dst) histogram
// ---------------------------------------------------------------------------
__global__ __launch_bounds__(256) void zero_i32(int* __restrict__ p, int n) {
    int i = blockIdx.x * 256 + threadIdx.x;
    if (i < n) p[i] = 0;
}

// ---------------------------------------------------------------------------
// fused: {row histogram (1 edge/thread — round-5 A/B showed wave-TLP wins
// over per-thread MLP for atomic chains) | nodes fp32->bf16 | weights->frags}
// block ranges: [0,EB) count, [EB,EB+CB) conv_nodes, [EB+CB, +WB) conv_weights
// ---------------------------------------------------------------------------
__global__ __launch_bounds__(256)
void prep2(const int* __restrict__ rows, int* __restrict__ cnt, int nnz,
           const float* __restrict__ nodes, unsigned short* __restrict__ ndbf, int N,
           const float* __restrict__ weights, short8* __restrict__ Wf,
           int EB, int CB) {
    int b = blockIdx.x;
    int t = threadIdx.x;
    if (b < EB) {                       // histogram over row id (r*N+dst)
        int e = b * 256 + t;
        if (e < nnz) atomicAdd(&cnt[rows[e]], 1);
        return;
    }
    b -= EB;
    if (b < CB) {                       // nodes fp32 -> bf16, row-major
        int id = b * 256 + t;           // id over N*16 (8 feats each)
        if (id < N * 16) {
            int n  = id >> 4;
            int k8 = id & 15;
            const float4* s = reinterpret_cast<const float4*>(nodes);
            float4 v0 = s[(size_t)n * 32 + k8 * 2];
            float4 v1 = s[(size_t)n * 32 + k8 * 2 + 1];
            short8 sv;
            sv[0] = f2bf(v0.x); sv[1] = f2bf(v0.y); sv[2] = f2bf(v0.z); sv[3] = f2bf(v0.w);
            sv[4] = f2bf(v1.x); sv[5] = f2bf(v1.y); sv[6] = f2bf(v1.z); sv[7] = f2bf(v1.w);
            *reinterpret_cast<short8*>(&ndbf[(size_t)n * HFR + k8 * 8]) = sv;
        }
        return;
    }
    b -= CB;                            // weights -> fragment layout (16384 ids)
    int id = b * 256 + t;
    int lane = id & 63;
    int kk   = (id >> 6) & 3;
    int j    = (id >> 8) & 7;
    int r    = id >> 11;
    int m = lane & 15, q = lane >> 4;
    const float* src = weights + (((size_t)r * HFR) + j * 16 + m) * HTO + kk * 32 + q * 8;
    short8 sv;
#pragma unroll
    for (int e = 0; e < 8; ++e) sv[e] = f2bf(src[e]);
    Wf[((r * 4 + kk) * 8 + j) * 64 + lane] = sv;
}

// ---------------------------------------------------------------------------
// 2-level exclusive scan: scan_reduce (per-256 sums), scan_block4 (single
// block scans up to 4096 block-sums, 4/thread), scan_final (apply).
// ---------------------------------------------------------------------------
__global__ __launch_bounds__(256)
void scan_reduce(const int* __restrict__ cnt, int* __restrict__ bsum, int N) {
    __shared__ int s[256];
    int t = threadIdx.x;
    int i = blockIdx.x * 256 + t;
    s[t] = (i < N) ? cnt[i] : 0;
    __syncthreads();
    for (int off = 128; off > 0; off >>= 1) {
        if (t < off) s[t] += s[t + off];
        __syncthreads();
    }
    if (t == 0) bsum[blockIdx.x] = s[0];
}

__global__ __launch_bounds__(1024)
void scan_block4(int* __restrict__ b, int n) {   // n <= 4096
    __shared__ int s[1024];
    int t  = threadIdx.x;
    int i0 = t * 4;
    int v0 = (i0     < n) ? b[i0]     : 0;
    int v1 = (i0 + 1 < n) ? b[i0 + 1] : 0;
    int v2 = (i0 + 2 < n) ? b[i0 + 2] : 0;
    int v3 = (i0 + 3 < n) ? b[i0 + 3] : 0;
    s[t] = v0 + v1 + v2 + v3;
    __syncthreads();
    for (int off = 1; off < 1024; off <<= 1) {
        int o = (t >= off) ? s[t - off] : 0;
        __syncthreads();
        s[t] += o;
        __syncthreads();
    }
    int ex = (t == 0) ? 0 : s[t - 1];
    if (i0     < n) b[i0]     = ex;
    if (i0 + 1 < n) b[i0 + 1] = ex + v0;
    if (i0 + 2 < n) b[i0 + 2] = ex + v0 + v1;
    if (i0 + 3 < n) b[i0 + 3] = ex + v0 + v1 + v2;
}

__global__ __launch_bounds__(256)
void scan_final(int* __restrict__ cnt, const int* __restrict__ bsum, int N) {
    __shared__ int s[256];
    int t = threadIdx.x;
    int i = blockIdx.x * 256 + t;
    int v = (i < N) ? cnt[i] : 0;
    s[t] = v;
    __syncthreads();
    for (int off = 1; off < 256; off <<= 1) {
        int o = (t >= off) ? s[t - off] : 0;
        __syncthreads();
        s[t] += o;
        __syncthreads();
    }
    int ex = ((t == 0) ? 0 : s[t - 1]) + bsum[blockIdx.x];
    if (i < N) cnt[i] = ex;     // cnt becomes the segment-start cursor
}

// ---------------------------------------------------------------------------
// counting-sort placement, 1 edge/thread (25K waves saturate all wave slots;
// round-5 showed batching regresses this). sorted[] ordered by row id.
// ---------------------------------------------------------------------------
__global__ __launch_bounds__(256)
void place_kernel(const int* __restrict__ rows, const int* __restrict__ cols,
                  const float* __restrict__ vals,
                  int* __restrict__ cursor, u64* __restrict__ sorted, int nnz) {
    int e = blockIdx.x * 256 + threadIdx.x;
    if (e >= nnz) return;
    int row = rows[e];
    int pos = atomicAdd(&cursor[row], 1);
    sorted[pos] = make_rec(vals[e], row, cols[e]);
}

// ---------------------------------------------------------------------------
// AGG v2: wave owns RW=8 consecutive rows; streams its contiguous edge range
// in unguarded batches of 8 (8 record loads -> 8 independent gathers), with
// wave-uniform row-boundary flush driven by the row15 tag in each record.
// Only 2 cursor reads per wave. Zero LDS, zero barriers.
// ---------------------------------------------------------------------------
__global__ __launch_bounds__(256)
void agg_kernel(const unsigned short* __restrict__ ndbf,
                const u64* __restrict__ sorted,
                const int* __restrict__ cursor,
                uint* __restrict__ aggp, int NR) {
    int gw   = blockIdx.x * 4 + (threadIdx.x >> 6);
    int lane = threadIdx.x & 63;
    int v0   = gw * RW;
    if (v0 >= NR) return;
    int vend = min(v0 + RW, NR);
    int nrows = vend - v0;

    const uint* nd32 = reinterpret_cast<const uint*>(ndbf);

    int e    = (v0 == 0) ? 0 : cursor[v0 - 1];
    int eend = cursor[vend - 1];

    uint  vtag = (uint)v0 & 0x7FFFu;
    int   cur  = 0;
    float a0 = 0.f, a1 = 0.f;

#define GATH(q)  nd32[(size_t)((uint)(q) & 0x1FFFFu) * 64 + lane]
#define PROC(q, x) {                                                          \
        int rd = (int)((((uint)(q) >> 17) - vtag) & 0x7FFFu);                 \
        while (cur < rd) {                                                    \
            aggp[(size_t)(v0 + cur) * 64 + lane] =                            \
                ((uint)f2bf(a1) << 16) | (uint)f2bf(a0);                      \
            a0 = 0.f; a1 = 0.f; ++cur;                                        \
        }                                                                     \
        float v = __uint_as_float((uint)((q) >> 32));                         \
        a0 = fmaf(bflo(x), v, a0); a1 = fmaf(bfhi(x), v, a1);                 \
    }

    for (; e + 8 <= eend; e += 8) {
        const u64* p = sorted + __builtin_amdgcn_readfirstlane(e);
        u64 q0 = p[0], q1 = p[1], q2 = p[2], q3 = p[3];
        u64 q4 = p[4], q5 = p[5], q6 = p[6], q7 = p[7];
        uint x0 = GATH(q0);
        uint x1 = GATH(q1);
        uint x2 = GATH(q2);
        uint x3 = GATH(q3);
        uint x4 = GATH(q4);
        uint x5 = GATH(q5);
        uint x6 = GATH(q6);
        uint x7 = GATH(q7);
        PROC(q0, x0) PROC(q1, x1) PROC(q2, x2) PROC(q3, x3)
        PROC(q4, x4) PROC(q5, x5) PROC(q6, x6) PROC(q7, x7)
    }
    for (; e < eend; ++e) {
        u64 q0 = sorted[e];
        uint x0 = GATH(q0);
        PROC(q0, x0)
    }
    for (; cur < nrows; ++cur) {
        aggp[(size_t)(v0 + cur) * 64 + lane] =
            ((uint)f2bf(a1) << 16) | (uint)f2bf(a0);
        a0 = 0.f; a1 = 0.f;
    }
#undef PROC
#undef GATH
}

// ---------------------------------------------------------------------------
// GEMM: out[n] = relu( sum_r W_r * agg[r*N+n] ), registers across r.
// unroll 2 on r: compiler can issue r+1's B-frag loads under r's 64 MFMAs.
// ---------------------------------------------------------------------------
__global__ __launch_bounds__(256)
void gemm_kernel(const uint* __restrict__ aggp, const short8* __restrict__ Wf,
                 float* __restrict__ out, int N, int R) {
    const int t    = threadIdx.x;
    const int lane = t & 63;
    const int w    = t >> 6;
    const int m    = lane & 15;
    const int quad = lane >> 4;
    const int nb   = blockIdx.x * 128 + w * 32;   // wave's 32-node base

    f32x4 acc[2][8];
#pragma unroll
    for (int s = 0; s < 2; ++s)
#pragma unroll
        for (int j = 0; j < 8; ++j) acc[s][j] = (f32x4)(0.f);

#pragma unroll 2
    for (int r = 0; r < R; ++r) {
        short8 b[2][4];
#pragma unroll
        for (int s = 0; s < 2; ++s) {
            int n = nb + s * 16 + m;
            if (n < N) {
                const short8* rowp = reinterpret_cast<const short8*>(
                    aggp + ((size_t)r * N + n) * 64);
#pragma unroll
                for (int kk = 0; kk < 4; ++kk) b[s][kk] = rowp[kk * 4 + quad];
            } else {
#pragma unroll
                for (int kk = 0; kk < 4; ++kk) b[s][kk] = (short8)(short)0;
            }
        }
        const short8* wr = Wf + (size_t)r * 2048 + lane;
#pragma unroll
        for (int kk = 0; kk < 4; ++kk)
#pragma unroll
            for (int j = 0; j < 8; ++j) {
                short8 aw = wr[kk * 512 + j * 64];
                acc[0][j] = __builtin_amdgcn_mfma_f32_16x16x32_bf16(aw, b[0][kk], acc[0][j], 0, 0, 0);
                acc[1][j] = __builtin_amdgcn_mfma_f32_16x16x32_bf16(aw, b[1][kk], acc[1][j], 0, 0, 0);
            }
    }

#pragma unroll
    for (int s = 0; s < 2; ++s) {
        int n = nb + s * 16 + m;
        if (n < N) {
#pragma unroll
            for (int j = 0; j < 8; ++j) {
                float4 o;
                o.x = fmaxf(acc[s][j][0], 0.f);
                o.y = fmaxf(acc[s][j][1], 0.f);
                o.z = fmaxf(acc[s][j][2], 0.f);
                o.w = fmaxf(acc[s][j][3], 0.f);
                *reinterpret_cast<float4*>(out + (size_t)n * HTO + j * 16 + quad * 4) = o;
            }
        }
    }
}

// ---------------------------------------------------------------------------
extern "C" void kernel_launch(void* const* d_in, const int* in_sizes, int n_in,
                              void* d_out, int out_size, void* d_ws, size_t ws_size,
                              hipStream_t stream) {
    const float* nodes   = (const float*)d_in[0];   // [N, HFR] fp32
    const int*   indices = (const int*)d_in[1];     // [2, NNZ] int32
    const float* vals    = (const float*)d_in[2];   // [NNZ] fp32
    const float* weights = (const float*)d_in[3];   // [R, HFR, HTO] fp32

    const int N   = in_sizes[0] / HFR;
    const int nnz = in_sizes[1] / 2;
    const int R   = in_sizes[3] / (HFR * HTO);
    const int NR  = N * R;

    const int* rows = indices;
    const int* cols = indices + nnz;

    // ws (217.9 MB): aggp [NR,128] bf16 | sorted [nnz] u64 | Wf 256KB
    char* ws = (char*)d_ws;
    uint* aggp = (uint*)ws;                          // NR * 64 uints
    size_t off = (size_t)NR * 64 * sizeof(uint);
    u64* sorted = (u64*)(ws + off);
    off += (size_t)nnz * sizeof(u64);
    short8* Wf = (short8*)(ws + off);

    // d_out scratch (28.8 MB, all dead before gemm writes out):
    //   ndbf [N,HFR] bf16 | cnt [NR] int | b1
    char* ob = (char*)d_out;
    unsigned short* ndbf = (unsigned short*)ob;
    size_t ooff = (size_t)N * HFR * sizeof(unsigned short);
    int* cnt = (int*)(ob + ooff);
    ooff += (size_t)NR * sizeof(int);
    const int NB1 = (NR + 255) / 256;                // 3125 (<= 4096)
    int* b1 = (int*)(ob + ooff);

    float* out = (float*)d_out;

    const int EB  = (nnz + 255) / 256;               // 6250 count blocks
    const int CB  = (N * 16 + 255) / 256;            // 6250
    const int WB  = (R * 4 * 8 * 64) / 256;          // 64
    const int PB  = (nnz + 255) / 256;               // 6250 place blocks
    const int AB  = ((NR + RW - 1) / RW + 3) / 4;    // 25000 agg blocks
    const int GB  = (N + 127) / 128;                 // 782 gemm blocks

    // 1) zero histogram
    zero_i32<<<NB1, 256, 0, stream>>>(cnt, NR);
    // 2) fused: row histogram | nodes->bf16 | weights->frags
    prep2<<<EB + CB + WB, 256, 0, stream>>>(rows, cnt, nnz, nodes, ndbf, N,
                                            weights, Wf, EB, CB);
    // 3) 2-level exclusive scan of 800K counters
    scan_reduce<<<NB1, 256, 0, stream>>>(cnt, b1, NR);
    scan_block4<<<1, 1024, 0, stream>>>(b1, NB1);
    scan_final<<<NB1, 256, 0, stream>>>(cnt, b1, NR);
    // 4) counting-sort placement (sorted by row id)
    place_kernel<<<PB, 256, 0, stream>>>(rows, cols, vals, cnt, sorted, nnz);
    // 5) aggregate (edge-streaming, batched gathers)
    agg_kernel<<<AB, 256, 0, stream>>>(ndbf, sorted, cnt, aggp, NR);
    // 6) batched GEMM over relations + relu
    gemm_kernel<<<GB, 256, 0, stream>>>(aggp, Wf, out, N, R);
}

// Round 8
// 451.755 us; speedup vs baseline: 1.1213x; 1.0439x over previous
//
#include <hip/hip_runtime.h>
#include <hip/hip_bf16.h>
#include <stdint.h>

#define HFR 128
#define HTO 128
#define RW  8     // rows per agg wave

typedef short short8 __attribute__((ext_vector_type(8)));   // 8 bf16 = 4 VGPRs
typedef float f32x4  __attribute__((ext_vector_type(4)));   // MFMA C/D
typedef unsigned long long u64;
typedef unsigned int uint;

static __device__ __forceinline__ unsigned short f2bf(float x) {
    __hip_bfloat16 h = __float2bfloat16(x);
    return *reinterpret_cast<unsigned short*>(&h);
}
static __device__ __forceinline__ float bflo(uint x) {
    return __uint_as_float(x << 16);           // low bf16 -> f32
}
static __device__ __forceinline__ float bfhi(uint x) {
    return __uint_as_float(x & 0xffff0000u);   // high bf16 -> f32
}

// record: val[63:32] | row15[31:17] | col[16:0]   (col < 2^17, row mod 2^15)
static __device__ __forceinline__ u64 make_rec(float v, int row, int col) {
    return ((u64)__float_as_uint(v) << 32) |
           ((u64)((uint)row & 0x7FFFu) << 17) | (u64)(uint)col;
}

// ---------------------------------------------------------------------------
// zero the (r,dst) histogram
// ---------------------------------------------------------------------------
__global__ __launch_bounds__(256) void zero_i32(int* __restrict__ p, int n) {
    int i = blockIdx.x * 256 + threadIdx.x;
    if (i < n) p[i] = 0;
}

// ---------------------------------------------------------------------------
// fused: {row histogram (1 edge/thread — round-5 A/B showed wave-TLP wins
// over per-thread MLP for atomic chains) | nodes fp32->bf16 | weights->frags}
// block ranges: [0,EB) count, [EB,EB+CB) conv_nodes, [EB+CB, +WB) conv_weights
// ---------------------------------------------------------------------------
__global__ __launch_bounds__(256)
void prep2(const int* __restrict__ rows, int* __restrict__ cnt, int nnz,
           const float* __restrict__ nodes, unsigned short* __restrict__ ndbf, int N,
           const float* __restrict__ weights, short8* __restrict__ Wf,
           int EB, int CB) {
    int b = blockIdx.x;
    int t = threadIdx.x;
    if (b < EB) {                       // histogram over row id (r*N+dst)
        int e = b * 256 + t;
        if (e < nnz) atomicAdd(&cnt[rows[e]], 1);
        return;
    }
    b -= EB;
    if (b < CB) {                       // nodes fp32 -> bf16, row-major
        int id = b * 256 + t;           // id over N*16 (8 feats each)
        if (id < N * 16) {
            int n  = id >> 4;
            int k8 = id & 15;
            const float4* s = reinterpret_cast<const float4*>(nodes);
            float4 v0 = s[(size_t)n * 32 + k8 * 2];
            float4 v1 = s[(size_t)n * 32 + k8 * 2 + 1];
            short8 sv;
            sv[0] = f2bf(v0.x); sv[1] = f2bf(v0.y); sv[2] = f2bf(v0.z); sv[3] = f2bf(v0.w);
            sv[4] = f2bf(v1.x); sv[5] = f2bf(v1.y); sv[6] = f2bf(v1.z); sv[7] = f2bf(v1.w);
            *reinterpret_cast<short8*>(&ndbf[(size_t)n * HFR + k8 * 8]) = sv;
        }
        return;
    }
    b -= CB;                            // weights -> fragment layout (16384 ids)
    int id = b * 256 + t;
    int lane = id & 63;
    int kk   = (id >> 6) & 3;
    int j    = (id >> 8) & 7;
    int r    = id >> 11;
    int m = lane & 15, q = lane >> 4;
    const float* src = weights + (((size_t)r * HFR) + j * 16 + m) * HTO + kk * 32 + q * 8;
    short8 sv;
#pragma unroll
    for (int e = 0; e < 8; ++e) sv[e] = f2bf(src[e]);
    Wf[((r * 4 + kk) * 8 + j) * 64 + lane] = sv;
}

// ---------------------------------------------------------------------------
// 2-level exclusive scan: scan_reduce (per-256 sums), scan_block4 (single
// block scans up to 4096 block-sums, 4/thread), scan_final (apply).
// ---------------------------------------------------------------------------
__global__ __launch_bounds__(256)
void scan_reduce(const int* __restrict__ cnt, int* __restrict__ bsum, int N) {
    __shared__ int s[256];
    int t = threadIdx.x;
    int i = blockIdx.x * 256 + t;
    s[t] = (i < N) ? cnt[i] : 0;
    __syncthreads();
    for (int off = 128; off > 0; off >>= 1) {
        if (t < off) s[t] += s[t + off];
        __syncthreads();
    }
    if (t == 0) bsum[blockIdx.x] = s[0];
}

__global__ __launch_bounds__(1024)
void scan_block4(int* __restrict__ b, int n) {   // n <= 4096
    __shared__ int s[1024];
    int t  = threadIdx.x;
    int i0 = t * 4;
    int v0 = (i0     < n) ? b[i0]     : 0;
    int v1 = (i0 + 1 < n) ? b[i0 + 1] : 0;
    int v2 = (i0 + 2 < n) ? b[i0 + 2] : 0;
    int v3 = (i0 + 3 < n) ? b[i0 + 3] : 0;
    s[t] = v0 + v1 + v2 + v3;
    __syncthreads();
    for (int off = 1; off < 1024; off <<= 1) {
        int o = (t >= off) ? s[t - off] : 0;
        __syncthreads();
        s[t] += o;
        __syncthreads();
    }
    int ex = (t == 0) ? 0 : s[t - 1];
    if (i0     < n) b[i0]     = ex;
    if (i0 + 1 < n) b[i0 + 1] = ex + v0;
    if (i0 + 2 < n) b[i0 + 2] = ex + v0 + v1;
    if (i0 + 3 < n) b[i0 + 3] = ex + v0 + v1 + v2;
}

__global__ __launch_bounds__(256)
void scan_final(int* __restrict__ cnt, const int* __restrict__ bsum, int N) {
    __shared__ int s[256];
    int t = threadIdx.x;
    int i = blockIdx.x * 256 + t;
    int v = (i < N) ? cnt[i] : 0;
    s[t] = v;
    __syncthreads();
    for (int off = 1; off < 256; off <<= 1) {
        int o = (t >= off) ? s[t - off] : 0;
        __syncthreads();
        s[t] += o;
        __syncthreads();
    }
    int ex = ((t == 0) ? 0 : s[t - 1]) + bsum[blockIdx.x];
    if (i < N) cnt[i] = ex;     // cnt becomes the segment-start cursor
}

// ---------------------------------------------------------------------------
// counting-sort placement, 1 edge/thread (25K waves saturate all wave slots;
// round-5 showed batching regresses this). sorted[] ordered by row id.
// ---------------------------------------------------------------------------
__global__ __launch_bounds__(256)
void place_kernel(const int* __restrict__ rows, const int* __restrict__ cols,
                  const float* __restrict__ vals,
                  int* __restrict__ cursor, u64* __restrict__ sorted, int nnz) {
    int e = blockIdx.x * 256 + threadIdx.x;
    if (e >= nnz) return;
    int row = rows[e];
    int pos = atomicAdd(&cursor[row], 1);
    sorted[pos] = make_rec(vals[e], row, cols[e]);
}

// ---------------------------------------------------------------------------
// AGG v2: wave owns RW=8 consecutive rows; streams its contiguous edge range
// in unguarded batches of 8 (8 record loads -> 8 independent gathers), with
// wave-uniform row-boundary flush driven by the row15 tag in each record.
// Only 2 cursor reads per wave. Zero LDS, zero barriers.
// ---------------------------------------------------------------------------
__global__ __launch_bounds__(256)
void agg_kernel(const unsigned short* __restrict__ ndbf,
                const u64* __restrict__ sorted,
                const int* __restrict__ cursor,
                uint* __restrict__ aggp, int NR) {
    int gw   = blockIdx.x * 4 + (threadIdx.x >> 6);
    int lane = threadIdx.x & 63;
    int v0   = gw * RW;
    if (v0 >= NR) return;
    int vend = min(v0 + RW, NR);
    int nrows = vend - v0;

    const uint* nd32 = reinterpret_cast<const uint*>(ndbf);

    int e    = (v0 == 0) ? 0 : cursor[v0 - 1];
    int eend = cursor[vend - 1];

    uint  vtag = (uint)v0 & 0x7FFFu;
    int   cur  = 0;
    float a0 = 0.f, a1 = 0.f;

#define GATH(q)  nd32[(size_t)((uint)(q) & 0x1FFFFu) * 64 + lane]
#define PROC(q, x) {                                                          \
        int rd = (int)((((uint)(q) >> 17) - vtag) & 0x7FFFu);                 \
        while (cur < rd) {                                                    \
            aggp[(size_t)(v0 + cur) * 64 + lane] =                            \
                ((uint)f2bf(a1) << 16) | (uint)f2bf(a0);                      \
            a0 = 0.f; a1 = 0.f; ++cur;                                        \
        }                                                                     \
        float v = __uint_as_float((uint)((q) >> 32));                         \
        a0 = fmaf(bflo(x), v, a0); a1 = fmaf(bfhi(x), v, a1);                 \
    }

    for (; e + 8 <= eend; e += 8) {
        const u64* p = sorted + __builtin_amdgcn_readfirstlane(e);
        u64 q0 = p[0], q1 = p[1], q2 = p[2], q3 = p[3];
        u64 q4 = p[4], q5 = p[5], q6 = p[6], q7 = p[7];
        uint x0 = GATH(q0);
        uint x1 = GATH(q1);
        uint x2 = GATH(q2);
        uint x3 = GATH(q3);
        uint x4 = GATH(q4);
        uint x5 = GATH(q5);
        uint x6 = GATH(q6);
        uint x7 = GATH(q7);
        PROC(q0, x0) PROC(q1, x1) PROC(q2, x2) PROC(q3, x3)
        PROC(q4, x4) PROC(q5, x5) PROC(q6, x6) PROC(q7, x7)
    }
    for (; e < eend; ++e) {
        u64 q0 = sorted[e];
        uint x0 = GATH(q0);
        PROC(q0, x0)
    }
    for (; cur < nrows; ++cur) {
        aggp[(size_t)(v0 + cur) * 64 + lane] =
            ((uint)f2bf(a1) << 16) | (uint)f2bf(a0);
        a0 = 0.f; a1 = 0.f;
    }
#undef PROC
#undef GATH
}

// ---------------------------------------------------------------------------
// GEMM v2: out[n] = relu( sum_r W_r * agg[r*N+n] ).
// Round-7 fix (register-starved MLP): VGPR was 72 -> compiler serialized Wf
// loads into 32 load->use chains/relation. Now: aw[8] batch per kk (8
// independent L2 loads in flight), bn[2][4] next-relation prefetch under
// current MFMAs, launch_bounds(256,2) to allow ~176 VGPRs.
// ---------------------------------------------------------------------------
__global__ __launch_bounds__(256, 2)
void gemm_kernel(const uint* __restrict__ aggp, const short8* __restrict__ Wf,
                 float* __restrict__ out, int N, int R) {
    const int t    = threadIdx.x;
    const int lane = t & 63;
    const int w    = t >> 6;
    const int m    = lane & 15;
    const int quad = lane >> 4;
    const int nb   = blockIdx.x * 128 + w * 32;   // wave's 32-node base

    f32x4 acc[2][8];
#pragma unroll
    for (int s = 0; s < 2; ++s)
#pragma unroll
        for (int j = 0; j < 8; ++j) acc[s][j] = (f32x4)(0.f);

#define LOADB(RR, BB)                                                         \
    {                                                                         \
        _Pragma("unroll")                                                     \
        for (int s = 0; s < 2; ++s) {                                         \
            int n = nb + s * 16 + m;                                          \
            if (n < N) {                                                      \
                const short8* rowp = reinterpret_cast<const short8*>(         \
                    aggp + ((size_t)(RR) * N + n) * 64);                      \
                _Pragma("unroll")                                             \
                for (int kk = 0; kk < 4; ++kk) BB[s][kk] = rowp[kk * 4 + quad]; \
            } else {                                                          \
                _Pragma("unroll")                                             \
                for (int kk = 0; kk < 4; ++kk) BB[s][kk] = (short8)(short)0;  \
            }                                                                 \
        }                                                                     \
    }

    short8 b[2][4];
    LOADB(0, b)

    for (int r = 0; r < R; ++r) {
        short8 bn[2][4];
        if (r + 1 < R) LOADB(r + 1, bn)

        const short8* wr = Wf + (size_t)r * 2048 + lane;
#pragma unroll
        for (int kk = 0; kk < 4; ++kk) {
            short8 aw[8];
#pragma unroll
            for (int j = 0; j < 8; ++j) aw[j] = wr[kk * 512 + j * 64];
#pragma unroll
            for (int j = 0; j < 8; ++j) {
                acc[0][j] = __builtin_amdgcn_mfma_f32_16x16x32_bf16(aw[j], b[0][kk], acc[0][j], 0, 0, 0);
                acc[1][j] = __builtin_amdgcn_mfma_f32_16x16x32_bf16(aw[j], b[1][kk], acc[1][j], 0, 0, 0);
            }
        }

        if (r + 1 < R) {
#pragma unroll
            for (int s = 0; s < 2; ++s)
#pragma unroll
                for (int kk = 0; kk < 4; ++kk) b[s][kk] = bn[s][kk];
        }
    }
#undef LOADB

#pragma unroll
    for (int s = 0; s < 2; ++s) {
        int n = nb + s * 16 + m;
        if (n < N) {
#pragma unroll
            for (int j = 0; j < 8; ++j) {
                float4 o;
                o.x = fmaxf(acc[s][j][0], 0.f);
                o.y = fmaxf(acc[s][j][1], 0.f);
                o.z = fmaxf(acc[s][j][2], 0.f);
                o.w = fmaxf(acc[s][j][3], 0.f);
                *reinterpret_cast<float4*>(out + (size_t)n * HTO + j * 16 + quad * 4) = o;
            }
        }
    }
}

// ---------------------------------------------------------------------------
extern "C" void kernel_launch(void* const* d_in, const int* in_sizes, int n_in,
                              void* d_out, int out_size, void* d_ws, size_t ws_size,
                              hipStream_t stream) {
    const float* nodes   = (const float*)d_in[0];   // [N, HFR] fp32
    const int*   indices = (const int*)d_in[1];     // [2, NNZ] int32
    const float* vals    = (const float*)d_in[2];   // [NNZ] fp32
    const float* weights = (const float*)d_in[3];   // [R, HFR, HTO] fp32

    const int N   = in_sizes[0] / HFR;
    const int nnz = in_sizes[1] / 2;
    const int R   = in_sizes[3] / (HFR * HTO);
    const int NR  = N * R;

    const int* rows = indices;
    const int* cols = indices + nnz;

    // ws (217.9 MB): aggp [NR,128] bf16 | sorted [nnz] u64 | Wf 256KB
    char* ws = (char*)d_ws;
    uint* aggp = (uint*)ws;                          // NR * 64 uints
    size_t off = (size_t)NR * 64 * sizeof(uint);
    u64* sorted = (u64*)(ws + off);
    off += (size_t)nnz * sizeof(u64);
    short8* Wf = (short8*)(ws + off);

    // d_out scratch (28.8 MB, all dead before gemm writes out):
    //   ndbf [N,HFR] bf16 | cnt [NR] int | b1
    char* ob = (char*)d_out;
    unsigned short* ndbf = (unsigned short*)ob;
    size_t ooff = (size_t)N * HFR * sizeof(unsigned short);
    int* cnt = (int*)(ob + ooff);
    ooff += (size_t)NR * sizeof(int);
    const int NB1 = (NR + 255) / 256;                // 3125 (<= 4096)
    int* b1 = (int*)(ob + ooff);

    float* out = (float*)d_out;

    const int EB  = (nnz + 255) / 256;               // 6250 count blocks
    const int CB  = (N * 16 + 255) / 256;            // 6250
    const int WB  = (R * 4 * 8 * 64) / 256;          // 64
    const int PB  = (nnz + 255) / 256;               // 6250 place blocks
    const int AB  = ((NR + RW - 1) / RW + 3) / 4;    // 25000 agg blocks
    const int GB  = (N + 127) / 128;                 // 782 gemm blocks

    // 1) zero histogram
    zero_i32<<<NB1, 256, 0, stream>>>(cnt, NR);
    // 2) fused: row histogram | nodes->bf16 | weights->frags
    prep2<<<EB + CB + WB, 256, 0, stream>>>(rows, cnt, nnz, nodes, ndbf, N,
                                            weights, Wf, EB, CB);
    // 3) 2-level exclusive scan of 800K counters
    scan_reduce<<<NB1, 256, 0, stream>>>(cnt, b1, NR);
    scan_block4<<<1, 1024, 0, stream>>>(b1, NB1);
    scan_final<<<NB1, 256, 0, stream>>>(cnt, b1, NR);
    // 4) counting-sort placement (sorted by row id)
    place_kernel<<<PB, 256, 0, stream>>>(rows, cols, vals, cnt, sorted, nnz);
    // 5) aggregate (edge-streaming, batched gathers)
    agg_kernel<<<AB, 256, 0, stream>>>(ndbf, sorted, cnt, aggp, NR);
    // 6) batched GEMM over relations + relu
    gemm_kernel<<<GB, 256, 0, stream>>>(aggp, Wf, out, N, R);
}

// Round 9
// 451.098 us; speedup vs baseline: 1.1229x; 1.0015x over previous
//
#include <hip/hip_runtime.h>
#include <hip/hip_bf16.h>
#include <stdint.h>

#define HFR 128
#define HTO 128
#define RW  8     // rows per agg wave

typedef short short8 __attribute__((ext_vector_type(8)));   // 8 bf16 = 4 VGPRs
typedef float f32x4  __attribute__((ext_vector_type(4)));   // MFMA C/D
typedef unsigned long long u64;
typedef unsigned int uint;

static __device__ __forceinline__ unsigned short f2bf(float x) {
    __hip_bfloat16 h = __float2bfloat16(x);
    return *reinterpret_cast<unsigned short*>(&h);
}
static __device__ __forceinline__ float bflo(uint x) {
    return __uint_as_float(x << 16);           // low bf16 -> f32
}
static __device__ __forceinline__ float bfhi(uint x) {
    return __uint_as_float(x & 0xffff0000u);   // high bf16 -> f32
}

// record: val[63:32] | row15[31:17] | col[16:0]   (col < 2^17, row mod 2^15)
static __device__ __forceinline__ u64 make_rec(float v, int row, int col) {
    return ((u64)__float_as_uint(v) << 32) |
           ((u64)((uint)row & 0x7FFFu) << 17) | (u64)(uint)col;
}

// ---------------------------------------------------------------------------
// zero the (r,dst) histogram
// ---------------------------------------------------------------------------
__global__ __launch_bounds__(256) void zero_i32(int* __restrict__ p, int n) {
    int i = blockIdx.x * 256 + threadIdx.x;
    if (i < n) p[i] = 0;
}

// ---------------------------------------------------------------------------
// fused: {row histogram (1 edge/thread — round-5 A/B showed wave-TLP wins
// over per-thread MLP for atomic chains) | nodes fp32->bf16 | weights->frags}
// block ranges: [0,EB) count, [EB,EB+CB) conv_nodes, [EB+CB, +WB) conv_weights
// ---------------------------------------------------------------------------
__global__ __launch_bounds__(256)
void prep2(const int* __restrict__ rows, int* __restrict__ cnt, int nnz,
           const float* __restrict__ nodes, unsigned short* __restrict__ ndbf, int N,
           const float* __restrict__ weights, short8* __restrict__ Wf,
           int EB, int CB) {
    int b = blockIdx.x;
    int t = threadIdx.x;
    if (b < EB) {                       // histogram over row id (r*N+dst)
        int e = b * 256 + t;
        if (e < nnz) atomicAdd(&cnt[rows[e]], 1);
        return;
    }
    b -= EB;
    if (b < CB) {                       // nodes fp32 -> bf16, row-major
        int id = b * 256 + t;           // id over N*16 (8 feats each)
        if (id < N * 16) {
            int n  = id >> 4;
            int k8 = id & 15;
            const float4* s = reinterpret_cast<const float4*>(nodes);
            float4 v0 = s[(size_t)n * 32 + k8 * 2];
            float4 v1 = s[(size_t)n * 32 + k8 * 2 + 1];
            short8 sv;
            sv[0] = f2bf(v0.x); sv[1] = f2bf(v0.y); sv[2] = f2bf(v0.z); sv[3] = f2bf(v0.w);
            sv[4] = f2bf(v1.x); sv[5] = f2bf(v1.y); sv[6] = f2bf(v1.z); sv[7] = f2bf(v1.w);
            *reinterpret_cast<short8*>(&ndbf[(size_t)n * HFR + k8 * 8]) = sv;
        }
        return;
    }
    b -= CB;                            // weights -> fragment layout (16384 ids)
    int id = b * 256 + t;
    int lane = id & 63;
    int kk   = (id >> 6) & 3;
    int j    = (id >> 8) & 7;
    int r    = id >> 11;
    int m = lane & 15, q = lane >> 4;
    const float* src = weights + (((size_t)r * HFR) + j * 16 + m) * HTO + kk * 32 + q * 8;
    short8 sv;
#pragma unroll
    for (int e = 0; e < 8; ++e) sv[e] = f2bf(src[e]);
    Wf[((r * 4 + kk) * 8 + j) * 64 + lane] = sv;
}

// ---------------------------------------------------------------------------
// 2-level exclusive scan: scan_reduce (per-256 sums), scan_block4 (single
// block scans up to 4096 block-sums, 4/thread), scan_final (apply).
// ---------------------------------------------------------------------------
__global__ __launch_bounds__(256)
void scan_reduce(const int* __restrict__ cnt, int* __restrict__ bsum, int N) {
    __shared__ int s[256];
    int t = threadIdx.x;
    int i = blockIdx.x * 256 + t;
    s[t] = (i < N) ? cnt[i] : 0;
    __syncthreads();
    for (int off = 128; off > 0; off >>= 1) {
        if (t < off) s[t] += s[t + off];
        __syncthreads();
    }
    if (t == 0) bsum[blockIdx.x] = s[0];
}

__global__ __launch_bounds__(1024)
void scan_block4(int* __restrict__ b, int n) {   // n <= 4096
    __shared__ int s[1024];
    int t  = threadIdx.x;
    int i0 = t * 4;
    int v0 = (i0     < n) ? b[i0]     : 0;
    int v1 = (i0 + 1 < n) ? b[i0 + 1] : 0;
    int v2 = (i0 + 2 < n) ? b[i0 + 2] : 0;
    int v3 = (i0 + 3 < n) ? b[i0 + 3] : 0;
    s[t] = v0 + v1 + v2 + v3;
    __syncthreads();
    for (int off = 1; off < 1024; off <<= 1) {
        int o = (t >= off) ? s[t - off] : 0;
        __syncthreads();
        s[t] += o;
        __syncthreads();
    }
    int ex = (t == 0) ? 0 : s[t - 1];
    if (i0     < n) b[i0]     = ex;
    if (i0 + 1 < n) b[i0 + 1] = ex + v0;
    if (i0 + 2 < n) b[i0 + 2] = ex + v0 + v1;
    if (i0 + 3 < n) b[i0 + 3] = ex + v0 + v1 + v2;
}

__global__ __launch_bounds__(256)
void scan_final(int* __restrict__ cnt, const int* __restrict__ bsum, int N) {
    __shared__ int s[256];
    int t = threadIdx.x;
    int i = blockIdx.x * 256 + t;
    int v = (i < N) ? cnt[i] : 0;
    s[t] = v;
    __syncthreads();
    for (int off = 1; off < 256; off <<= 1) {
        int o = (t >= off) ? s[t - off] : 0;
        __syncthreads();
        s[t] += o;
        __syncthreads();
    }
    int ex = ((t == 0) ? 0 : s[t - 1]) + bsum[blockIdx.x];
    if (i < N) cnt[i] = ex;     // cnt becomes the segment-start cursor
}

// ---------------------------------------------------------------------------
// counting-sort placement, XCD-sliced ownership (round 9):
// Positions for a contiguous row-slice are contiguous in sorted[], so if
// only blocks with (blockIdx&7)==s write slice s, each XCD's partial-sector
// writes merge in its 4MB L2 (slice = 1.6MB) before writeback -> ~full
// 64B sectors instead of 8x write amplification. Correctness does NOT
// depend on the blockIdx->XCD mapping (each edge owned by exactly one
// slice; masked disjoint-byte writebacks); only speed does.
// Each chunk of 2048 edges is scanned by 8 blocks (rows re-read 8x, L3-hot);
// cols/vals/atomic/store predicated to the ~1/8 owned lanes.
// ---------------------------------------------------------------------------
__global__ __launch_bounds__(256)
void place_kernel(const int* __restrict__ rows, const int* __restrict__ cols,
                  const float* __restrict__ vals,
                  int* __restrict__ cursor, u64* __restrict__ sorted,
                  int nnz, int NR) {
    const int s    = blockIdx.x & 7;
    const int blk  = blockIdx.x >> 3;
    const int lo   = (int)(((long long)s       * NR) >> 3);
    const int hi   = (int)(((long long)(s + 1) * NR) >> 3);
    const int base = blk * 2048;
    for (int it = 0; it < 8; ++it) {
        int e = base + it * 256 + threadIdx.x;
        if (e < nnz) {
            int row = rows[e];
            if (row >= lo && row < hi) {
                int pos = atomicAdd(&cursor[row], 1);
                sorted[pos] = make_rec(vals[e], row, cols[e]);
            }
        }
    }
}

// ---------------------------------------------------------------------------
// AGG v2: wave owns RW=8 consecutive rows; streams its contiguous edge range
// in unguarded batches of 8 (8 record loads -> 8 independent gathers), with
// wave-uniform row-boundary flush driven by the row15 tag in each record.
// Only 2 cursor reads per wave. Zero LDS, zero barriers.
// ---------------------------------------------------------------------------
__global__ __launch_bounds__(256)
void agg_kernel(const unsigned short* __restrict__ ndbf,
                const u64* __restrict__ sorted,
                const int* __restrict__ cursor,
                uint* __restrict__ aggp, int NR) {
    int gw   = blockIdx.x * 4 + (threadIdx.x >> 6);
    int lane = threadIdx.x & 63;
    int v0   = gw * RW;
    if (v0 >= NR) return;
    int vend = min(v0 + RW, NR);
    int nrows = vend - v0;

    const uint* nd32 = reinterpret_cast<const uint*>(ndbf);

    int e    = (v0 == 0) ? 0 : cursor[v0 - 1];
    int eend = cursor[vend - 1];

    uint  vtag = (uint)v0 & 0x7FFFu;
    int   cur  = 0;
    float a0 = 0.f, a1 = 0.f;

#define GATH(q)  nd32[(size_t)((uint)(q) & 0x1FFFFu) * 64 + lane]
#define PROC(q, x) {                                                          \
        int rd = (int)((((uint)(q) >> 17) - vtag) & 0x7FFFu);                 \
        while (cur < rd) {                                                    \
            aggp[(size_t)(v0 + cur) * 64 + lane] =                            \
                ((uint)f2bf(a1) << 16) | (uint)f2bf(a0);                      \
            a0 = 0.f; a1 = 0.f; ++cur;                                        \
        }                                                                     \
        float v = __uint_as_float((uint)((q) >> 32));                         \
        a0 = fmaf(bflo(x), v, a0); a1 = fmaf(bfhi(x), v, a1);                 \
    }

    for (; e + 8 <= eend; e += 8) {
        const u64* p = sorted + __builtin_amdgcn_readfirstlane(e);
        u64 q0 = p[0], q1 = p[1], q2 = p[2], q3 = p[3];
        u64 q4 = p[4], q5 = p[5], q6 = p[6], q7 = p[7];
        uint x0 = GATH(q0);
        uint x1 = GATH(q1);
        uint x2 = GATH(q2);
        uint x3 = GATH(q3);
        uint x4 = GATH(q4);
        uint x5 = GATH(q5);
        uint x6 = GATH(q6);
        uint x7 = GATH(q7);
        PROC(q0, x0) PROC(q1, x1) PROC(q2, x2) PROC(q3, x3)
        PROC(q4, x4) PROC(q5, x5) PROC(q6, x6) PROC(q7, x7)
    }
    for (; e < eend; ++e) {
        u64 q0 = sorted[e];
        uint x0 = GATH(q0);
        PROC(q0, x0)
    }
    for (; cur < nrows; ++cur) {
        aggp[(size_t)(v0 + cur) * 64 + lane] =
            ((uint)f2bf(a1) << 16) | (uint)f2bf(a0);
        a0 = 0.f; a1 = 0.f;
    }
#undef PROC
#undef GATH
}

// ---------------------------------------------------------------------------
// GEMM v2: out[n] = relu( sum_r W_r * agg[r*N+n] ).
// aw[8] batch per kk (8 independent L2 loads in flight), bn[2][4]
// next-relation prefetch under current MFMAs, launch_bounds(256,2).
// ---------------------------------------------------------------------------
__global__ __launch_bounds__(256, 2)
void gemm_kernel(const uint* __restrict__ aggp, const short8* __restrict__ Wf,
                 float* __restrict__ out, int N, int R) {
    const int t    = threadIdx.x;
    const int lane = t & 63;
    const int w    = t >> 6;
    const int m    = lane & 15;
    const int quad = lane >> 4;
    const int nb   = blockIdx.x * 128 + w * 32;   // wave's 32-node base

    f32x4 acc[2][8];
#pragma unroll
    for (int s = 0; s < 2; ++s)
#pragma unroll
        for (int j = 0; j < 8; ++j) acc[s][j] = (f32x4)(0.f);

#define LOADB(RR, BB)                                                         \
    {                                                                         \
        _Pragma("unroll")                                                     \
        for (int s = 0; s < 2; ++s) {                                         \
            int n = nb + s * 16 + m;                                          \
            if (n < N) {                                                      \
                const short8* rowp = reinterpret_cast<const short8*>(         \
                    aggp + ((size_t)(RR) * N + n) * 64);                      \
                _Pragma("unroll")                                             \
                for (int kk = 0; kk < 4; ++kk) BB[s][kk] = rowp[kk * 4 + quad]; \
            } else {                                                          \
                _Pragma("unroll")                                             \
                for (int kk = 0; kk < 4; ++kk) BB[s][kk] = (short8)(short)0;  \
            }                                                                 \
        }                                                                     \
    }

    short8 b[2][4];
    LOADB(0, b)

    for (int r = 0; r < R; ++r) {
        short8 bn[2][4];
        if (r + 1 < R) LOADB(r + 1, bn)

        const short8* wr = Wf + (size_t)r * 2048 + lane;
#pragma unroll
        for (int kk = 0; kk < 4; ++kk) {
            short8 aw[8];
#pragma unroll
            for (int j = 0; j < 8; ++j) aw[j] = wr[kk * 512 + j * 64];
#pragma unroll
            for (int j = 0; j < 8; ++j) {
                acc[0][j] = __builtin_amdgcn_mfma_f32_16x16x32_bf16(aw[j], b[0][kk], acc[0][j], 0, 0, 0);
                acc[1][j] = __builtin_amdgcn_mfma_f32_16x16x32_bf16(aw[j], b[1][kk], acc[1][j], 0, 0, 0);
            }
        }

        if (r + 1 < R) {
#pragma unroll
            for (int s = 0; s < 2; ++s)
#pragma unroll
                for (int kk = 0; kk < 4; ++kk) b[s][kk] = bn[s][kk];
        }
    }
#undef LOADB

#pragma unroll
    for (int s = 0; s < 2; ++s) {
        int n = nb + s * 16 + m;
        if (n < N) {
#pragma unroll
            for (int j = 0; j < 8; ++j) {
                float4 o;
                o.x = fmaxf(acc[s][j][0], 0.f);
                o.y = fmaxf(acc[s][j][1], 0.f);
                o.z = fmaxf(acc[s][j][2], 0.f);
                o.w = fmaxf(acc[s][j][3], 0.f);
                *reinterpret_cast<float4*>(out + (size_t)n * HTO + j * 16 + quad * 4) = o;
            }
        }
    }
}

// ---------------------------------------------------------------------------
extern "C" void kernel_launch(void* const* d_in, const int* in_sizes, int n_in,
                              void* d_out, int out_size, void* d_ws, size_t ws_size,
                              hipStream_t stream) {
    const float* nodes   = (const float*)d_in[0];   // [N, HFR] fp32
    const int*   indices = (const int*)d_in[1];     // [2, NNZ] int32
    const float* vals    = (const float*)d_in[2];   // [NNZ] fp32
    const float* weights = (const float*)d_in[3];   // [R, HFR, HTO] fp32

    const int N   = in_sizes[0] / HFR;
    const int nnz = in_sizes[1] / 2;
    const int R   = in_sizes[3] / (HFR * HTO);
    const int NR  = N * R;

    const int* rows = indices;
    const int* cols = indices + nnz;

    // ws (217.9 MB): aggp [NR,128] bf16 | sorted [nnz] u64 | Wf 256KB
    char* ws = (char*)d_ws;
    uint* aggp = (uint*)ws;                          // NR * 64 uints
    size_t off = (size_t)NR * 64 * sizeof(uint);
    u64* sorted = (u64*)(ws + off);
    off += (size_t)nnz * sizeof(u64);
    short8* Wf = (short8*)(ws + off);

    // d_out scratch (28.8 MB, all dead before gemm writes out):
    //   ndbf [N,HFR] bf16 | cnt [NR] int | b1
    char* ob = (char*)d_out;
    unsigned short* ndbf = (unsigned short*)ob;
    size_t ooff = (size_t)N * HFR * sizeof(unsigned short);
    int* cnt = (int*)(ob + ooff);
    ooff += (size_t)NR * sizeof(int);
    const int NB1 = (NR + 255) / 256;                // 3125 (<= 4096)
    int* b1 = (int*)(ob + ooff);

    float* out = (float*)d_out;

    const int EB  = (nnz + 255) / 256;               // 6250 count blocks
    const int CB  = (N * 16 + 255) / 256;            // 6250
    const int WB  = (R * 4 * 8 * 64) / 256;          // 64
    const int PB  = ((nnz + 2047) / 2048) * 8;       // 6256 place blocks (8 slices)
    const int AB  = ((NR + RW - 1) / RW + 3) / 4;    // 25000 agg blocks
    const int GB  = (N + 127) / 128;                 // 782 gemm blocks

    // 1) zero histogram
    zero_i32<<<NB1, 256, 0, stream>>>(cnt, NR);
    // 2) fused: row histogram | nodes->bf16 | weights->frags
    prep2<<<EB + CB + WB, 256, 0, stream>>>(rows, cnt, nnz, nodes, ndbf, N,
                                            weights, Wf, EB, CB);
    // 3) 2-level exclusive scan of 800K counters
    scan_reduce<<<NB1, 256, 0, stream>>>(cnt, b1, NR);
    scan_block4<<<1, 1024, 0, stream>>>(b1, NB1);
    scan_final<<<NB1, 256, 0, stream>>>(cnt, b1, NR);
    // 4) counting-sort placement (XCD-sliced, sorted by row id)
    place_kernel<<<PB, 256, 0, stream>>>(rows, cols, vals, cnt, sorted, nnz, NR);
    // 5) aggregate (edge-streaming, batched gathers)
    agg_kernel<<<AB, 256, 0, stream>>>(ndbf, sorted, cnt, aggp, NR);
    // 6) batched GEMM over relations + relu
    gemm_kernel<<<GB, 256, 0, stream>>>(aggp, Wf, out, N, R);
}